// Round 1
// baseline (158.539 us; speedup 1.0000x reference)
//
#include <hip/hip_runtime.h>
#include <math.h>

#define NQ 20
#define OUT_DIM 512
#define FAN_IN 21   // QOUT + COND_DIM
#define BATCH 262144

// ---------------------------------------------------------------------------
// Kernel 1: compute qout[w] analytically, then base[j] = b[j] + qout . W[j,:20]
// and wlast[j] = W[j,20].  One block of 512 threads.
//
// Closed form for <Z_w> of the 2-layer RY+CZ circuit (derived via transfer
// matrices; final CZ layer is diagonal -> no effect on probs):
//   <Z_w> = cos(p0[w])cos(p1[w]) - sin(p0[w])sin(p1[w]) * CL * CR
//   CL = cos(p0[w-1]) if w>0 else 1 ; CR = cos(p0[w+1]) if w<NQ-1 else 1
// ---------------------------------------------------------------------------
__global__ __launch_bounds__(OUT_DIM)
void prep_kernel(const float* __restrict__ params,  // (2, NQ) row-major
                 const float* __restrict__ W,       // (OUT_DIM, FAN_IN)
                 const float* __restrict__ b,       // (OUT_DIM,)
                 float* __restrict__ base,          // (OUT_DIM,)
                 float* __restrict__ wlast)         // (OUT_DIM,)
{
    __shared__ float qout[NQ];
    const int j = threadIdx.x;
    if (j < NQ) {
        float p0 = params[j];
        float p1 = params[NQ + j];
        float cl = (j > 0)      ? cosf(params[j - 1]) : 1.0f;
        float cr = (j < NQ - 1) ? cosf(params[j + 1]) : 1.0f;
        qout[j] = cosf(p0) * cosf(p1) - sinf(p0) * sinf(p1) * cl * cr;
    }
    __syncthreads();

    const float* wr = W + j * FAN_IN;
    float acc = b[j];
#pragma unroll
    for (int k = 0; k < NQ; ++k) acc += qout[k] * wr[k];
    base[j]  = acc;
    wlast[j] = wr[NQ];
}

// ---------------------------------------------------------------------------
// Kernel 2: out[i][j] = tanh(base[j] + cond[i]*wlast[j])
// Block = 256 threads -> 2 rows/block, 128 threads/row, float4 per thread.
// Pure write-BW bound: 512 MiB out, ~2 MiB in.
// ---------------------------------------------------------------------------
__device__ __forceinline__ float ftanh(float x) {
    // tanh(x) = 1 - 2/(e^{2x}+1); clamp so __expf never overflows.
    x = fminf(fmaxf(x, -10.0f), 10.0f);
    float e = __expf(2.0f * x);
    return 1.0f - 2.0f / (e + 1.0f);
}

__global__ __launch_bounds__(256)
void main_kernel(const float* __restrict__ cond,
                 const float* __restrict__ base,
                 const float* __restrict__ wlast,
                 float* __restrict__ out)
{
    const int t   = threadIdx.x;
    const int row = (blockIdx.x << 1) + (t >> 7);
    const int j   = (t & 127) << 2;          // column start (float4)

    const float c = cond[row];               // broadcast within half-wave
    float4 bs = *reinterpret_cast<const float4*>(base  + j);
    float4 wl = *reinterpret_cast<const float4*>(wlast + j);

    float4 r;
    r.x = ftanh(fmaf(c, wl.x, bs.x));
    r.y = ftanh(fmaf(c, wl.y, bs.y));
    r.z = ftanh(fmaf(c, wl.z, bs.z));
    r.w = ftanh(fmaf(c, wl.w, bs.w));

    *reinterpret_cast<float4*>(out + (size_t)row * OUT_DIM + j) = r;
}

extern "C" void kernel_launch(void* const* d_in, const int* in_sizes, int n_in,
                              void* d_out, int out_size, void* d_ws, size_t ws_size,
                              hipStream_t stream)
{
    const float* cond   = (const float*)d_in[0];  // (BATCH, 1)
    const float* params = (const float*)d_in[1];  // (2, NQ)
    const float* W      = (const float*)d_in[2];  // (OUT_DIM, FAN_IN)
    const float* b      = (const float*)d_in[3];  // (OUT_DIM,)
    float* out = (float*)d_out;

    float* base  = (float*)d_ws;          // OUT_DIM floats
    float* wlast = base + OUT_DIM;        // OUT_DIM floats

    prep_kernel<<<1, OUT_DIM, 0, stream>>>(params, W, b, base, wlast);

    const int rows_per_block = 2;
    const int nblocks = BATCH / rows_per_block;   // 131072
    main_kernel<<<nblocks, 256, 0, stream>>>(cond, base, wlast, out);
}

// Round 3
// 115.675 us; speedup vs baseline: 1.3706x; 1.3706x over previous
//
#include <hip/hip_runtime.h>
#include <math.h>

#define NQ 20
#define OUT_DIM 512
#define FAN_IN 21   // QOUT + COND_DIM
#define BATCH 262144
#define GRID 2048   // 8 blocks/CU on 256 CUs -> full occupancy, grid-stride

typedef float vfloat4 __attribute__((ext_vector_type(4)));  // native vector:
// __builtin_nontemporal_store requires a Clang vector type, not HIP float4.

// ---------------------------------------------------------------------------
// Kernel 1: qout[w] analytically, then base[j] = b[j] + qout . W[j,:20],
// wlast[j] = W[j,20].  One block of 512 threads.
//
// Closed form for <Z_w> of the 2-layer RY+CZ circuit (transfer matrices;
// final CZ layer is diagonal -> no effect on probs):
//   <Z_w> = cos(p0[w])cos(p1[w]) - sin(p0[w])sin(p1[w]) * CL * CR
//   CL = cos(p0[w-1]) if w>0 else 1 ; CR = cos(p0[w+1]) if w<NQ-1 else 1
// ---------------------------------------------------------------------------
__global__ __launch_bounds__(OUT_DIM)
void prep_kernel(const float* __restrict__ params,  // (2, NQ)
                 const float* __restrict__ W,       // (OUT_DIM, FAN_IN)
                 const float* __restrict__ b,       // (OUT_DIM,)
                 float* __restrict__ base,          // (OUT_DIM,)
                 float* __restrict__ wlast)         // (OUT_DIM,)
{
    __shared__ float qout[NQ];
    const int j = threadIdx.x;
    if (j < NQ) {
        float p0 = params[j];
        float p1 = params[NQ + j];
        float cl = (j > 0)      ? cosf(params[j - 1]) : 1.0f;
        float cr = (j < NQ - 1) ? cosf(params[j + 1]) : 1.0f;
        qout[j] = cosf(p0) * cosf(p1) - sinf(p0) * sinf(p1) * cl * cr;
    }
    __syncthreads();

    const float* wr = W + j * FAN_IN;
    float acc = b[j];
#pragma unroll
    for (int k = 0; k < NQ; ++k) acc += qout[k] * wr[k];
    base[j]  = acc;
    wlast[j] = wr[NQ];
}

// ---------------------------------------------------------------------------
// Kernel 2: out[i][j] = tanh(base[j] + cond[i]*wlast[j])
// Grid-stride: 2048 blocks x 256 threads. Each thread owns a fixed column
// quad (base/wlast in registers), loops over rows, nontemporal float4 store.
// ---------------------------------------------------------------------------
__device__ __forceinline__ float ftanh(float x) {
    x = fminf(fmaxf(x, -10.0f), 10.0f);
    float e = __expf(2.0f * x);
    return 1.0f - 2.0f / (e + 1.0f);
}

__global__ __launch_bounds__(256)
void main_kernel(const float* __restrict__ cond,
                 const float* __restrict__ base,
                 const float* __restrict__ wlast,
                 float* __restrict__ out)
{
    const int t    = threadIdx.x;
    const int half = t >> 7;               // 0/1: which row of the pair
    const int j    = (t & 127) << 2;       // column start (float4)

    const vfloat4 bs = *reinterpret_cast<const vfloat4*>(base  + j);
    const vfloat4 wl = *reinterpret_cast<const vfloat4*>(wlast + j);

    const int CHUNK = BATCH / GRID;        // 128 rows per block
    const int row0  = blockIdx.x * CHUNK + half;

#pragma unroll 4
    for (int r = 0; r < CHUNK; r += 2) {
        const int row = row0 + r;
        const float c = cond[row];         // wave-uniform -> scalar load
        vfloat4 o;
        o.x = ftanh(fmaf(c, wl.x, bs.x));
        o.y = ftanh(fmaf(c, wl.y, bs.y));
        o.z = ftanh(fmaf(c, wl.z, bs.z));
        o.w = ftanh(fmaf(c, wl.w, bs.w));
        __builtin_nontemporal_store(o,
            reinterpret_cast<vfloat4*>(out + (size_t)row * OUT_DIM + j));
    }
}

extern "C" void kernel_launch(void* const* d_in, const int* in_sizes, int n_in,
                              void* d_out, int out_size, void* d_ws, size_t ws_size,
                              hipStream_t stream)
{
    const float* cond   = (const float*)d_in[0];  // (BATCH, 1)
    const float* params = (const float*)d_in[1];  // (2, NQ)
    const float* W      = (const float*)d_in[2];  // (OUT_DIM, FAN_IN)
    const float* b      = (const float*)d_in[3];  // (OUT_DIM,)
    float* out = (float*)d_out;

    float* base  = (float*)d_ws;          // OUT_DIM floats
    float* wlast = base + OUT_DIM;        // OUT_DIM floats

    prep_kernel<<<1, OUT_DIM, 0, stream>>>(params, W, b, base, wlast);
    main_kernel<<<GRID, 256, 0, stream>>>(cond, base, wlast, out);
}

// Round 4
// 111.494 us; speedup vs baseline: 1.4219x; 1.0375x over previous
//
#include <hip/hip_runtime.h>
#include <math.h>

#define NQ 20
#define OUT_DIM 512
#define FAN_IN 21     // QOUT + COND_DIM
#define BATCH 262144
#define GRID 2048     // 8 blocks/CU * 256 CUs; each block owns 128 rows

typedef float vfloat4 __attribute__((ext_vector_type(4)));

// ---------------------------------------------------------------------------
// Fully fused kernel.
//   qout[w] = cos(p0[w])cos(p1[w]) - sin(p0[w])sin(p1[w])*CL*CR   (closed form,
//     CL/CR = cos(p0[w-/+1]) at interior, 1 at boundary; final CZ layer is
//     diagonal -> no effect on probabilities)
//   base[j] = b[j] + qout . W[j,:20];  wlast[j] = W[j,20]
//   out[i][j] = tanh(base[j] + cond[i]*wlast[j])
//
// Per block: stage cond[128 rows] + qout[20] in LDS, each thread computes its
// own 4 columns' (2*base, 2*wlast) once, then a pure store loop:
//   e = exp2((2*base + c*2*wlast)*log2e) via v_exp_f32; tanh = 1 - 2/(e+1).
// No clamp needed: e=inf -> 1, e=0 -> -1 exactly through v_rcp_f32.
// ---------------------------------------------------------------------------
__global__ __launch_bounds__(256)
void fused_kernel(const float* __restrict__ cond,
                  const float* __restrict__ params,
                  const float* __restrict__ W,
                  const float* __restrict__ b,
                  float* __restrict__ out)
{
    __shared__ float qout[NQ];
    __shared__ float sc[128];

    const int t = threadIdx.x;
    const int blk = blockIdx.x;

    if (t < 128) sc[t] = cond[blk * 128 + t];
    if (t < NQ) {
        float p0 = params[t];
        float p1 = params[NQ + t];
        float cl = (t > 0)      ? cosf(params[t - 1]) : 1.0f;
        float cr = (t < NQ - 1) ? cosf(params[t + 1]) : 1.0f;
        qout[t] = cosf(p0) * cosf(p1) - sinf(p0) * sinf(p1) * cl * cr;
    }
    __syncthreads();

    const int half = t >> 7;            // which row of each pair
    const int j    = (t & 127) << 2;    // column quad

    // Per-thread prep: A = 2*wlast, B = 2*base for columns j..j+3
    vfloat4 A, B;
#pragma unroll
    for (int r = 0; r < 4; ++r) {
        const float* wr = W + (j + r) * FAN_IN;
        float acc = b[j + r];
#pragma unroll
        for (int k = 0; k < NQ; ++k) acc += qout[k] * wr[k];
        B[r] = 2.0f * acc;
        A[r] = 2.0f * wr[NQ];
    }

    float* p = out + (size_t)(blk * 128 + half) * OUT_DIM + j;

#pragma unroll 8
    for (int r = 0; r < 64; ++r) {
        const float c = sc[2 * r + half];   // LDS broadcast, wave-uniform
        vfloat4 o;
#pragma unroll
        for (int q = 0; q < 4; ++q) {
            float e = __expf(fmaf(c, A[q], B[q]));   // e^{2x}
            o[q] = fmaf(-2.0f, __frcp_rn(e + 1.0f), 1.0f);
        }
        *reinterpret_cast<vfloat4*>(p) = o;
        p += 2 * OUT_DIM;                   // advance 2 rows
    }
}

extern "C" void kernel_launch(void* const* d_in, const int* in_sizes, int n_in,
                              void* d_out, int out_size, void* d_ws, size_t ws_size,
                              hipStream_t stream)
{
    const float* cond   = (const float*)d_in[0];  // (BATCH, 1)
    const float* params = (const float*)d_in[1];  // (2, NQ)
    const float* W      = (const float*)d_in[2];  // (OUT_DIM, FAN_IN)
    const float* b      = (const float*)d_in[3];  // (OUT_DIM,)
    float* out = (float*)d_out;

    fused_kernel<<<GRID, 256, 0, stream>>>(cond, params, W, b, out);
}

// Round 5
// 102.727 us; speedup vs baseline: 1.5433x; 1.0853x over previous
//
#include <hip/hip_runtime.h>
#include <math.h>

#define NQ 20
#define OUT_DIM 512
#define FAN_IN 21     // QOUT + COND_DIM
#define BATCH 262144
#define GRID 2048     // 8 blocks/CU * 256 CUs; each block owns 128 rows

typedef float vfloat4 __attribute__((ext_vector_type(4)));

// ---------------------------------------------------------------------------
// Kernel 1 (1 block, 512 threads): closed-form circuit + per-column prep.
//   qout[w] = cos(p0[w])cos(p1[w]) - sin(p0[w])sin(p1[w])*CL*CR
//     (CL/CR = cos(p0[w-/+1]) interior, 1 at boundary; trailing CZ layer is
//      diagonal -> no effect on probabilities)
//   B2[j] = 2*log2(e) * (b[j] + qout . W[j,:20])
//   A2[j] = 2*log2(e) * W[j,20]
// so that tanh(x) = 1 - 2/(2^(fma(c,A2,B2)) + 1).
// ---------------------------------------------------------------------------
__global__ __launch_bounds__(OUT_DIM)
void prep_kernel(const float* __restrict__ params,  // (2, NQ)
                 const float* __restrict__ W,       // (OUT_DIM, FAN_IN)
                 const float* __restrict__ b,       // (OUT_DIM,)
                 float* __restrict__ A2,            // (OUT_DIM,)
                 float* __restrict__ B2)            // (OUT_DIM,)
{
    __shared__ float qout[NQ];
    const int j = threadIdx.x;
    if (j < NQ) {
        float p0 = params[j];
        float p1 = params[NQ + j];
        float cl = (j > 0)      ? cosf(params[j - 1]) : 1.0f;
        float cr = (j < NQ - 1) ? cosf(params[j + 1]) : 1.0f;
        qout[j] = cosf(p0) * cosf(p1) - sinf(p0) * sinf(p1) * cl * cr;
    }
    __syncthreads();

    const float TWO_LOG2E = 2.8853900817779268f;  // 2*log2(e)
    const float* wr = W + j * FAN_IN;
    float acc = b[j];
#pragma unroll
    for (int k = 0; k < NQ; ++k) acc += qout[k] * wr[k];
    B2[j] = TWO_LOG2E * acc;
    A2[j] = TWO_LOG2E * wr[NQ];
}

// ---------------------------------------------------------------------------
// Kernel 2: out[i][j] = 1 - 2/(2^(fma(c_i, A2_j, B2_j)) + 1)
// 2048 blocks x 256 threads; block owns 128 rows; thread owns a column quad.
// A2/B2 loaded once as coalesced float4 (4 KB, L2-broadcast); cond staged in
// LDS; inner loop = 5 VALU/elem + one plain float4 store.
// ---------------------------------------------------------------------------
__global__ __launch_bounds__(256)
void main_kernel(const float* __restrict__ cond,
                 const float* __restrict__ A2,
                 const float* __restrict__ B2,
                 float* __restrict__ out)
{
    __shared__ float sc[128];
    const int t   = threadIdx.x;
    const int blk = blockIdx.x;
    const int half = t >> 7;            // which row of each pair
    const int j    = (t & 127) << 2;    // column quad

    if (t < 128) sc[t] = cond[blk * 128 + t];

    const vfloat4 A = *reinterpret_cast<const vfloat4*>(A2 + j);
    const vfloat4 B = *reinterpret_cast<const vfloat4*>(B2 + j);
    __syncthreads();

    float* p = out + (size_t)(blk * 128 + half) * OUT_DIM + j;

#pragma unroll 8
    for (int r = 0; r < 64; ++r) {
        const float c = sc[2 * r + half];   // LDS broadcast
        vfloat4 o;
#pragma unroll
        for (int q = 0; q < 4; ++q) {
            float e = __builtin_amdgcn_exp2f(fmaf(c, A[q], B[q]));  // e^{2x}
            o[q] = fmaf(-2.0f, __builtin_amdgcn_rcpf(e + 1.0f), 1.0f);
        }
        *reinterpret_cast<vfloat4*>(p) = o;
        p += 2 * OUT_DIM;                   // advance 2 rows
    }
}

extern "C" void kernel_launch(void* const* d_in, const int* in_sizes, int n_in,
                              void* d_out, int out_size, void* d_ws, size_t ws_size,
                              hipStream_t stream)
{
    const float* cond   = (const float*)d_in[0];  // (BATCH, 1)
    const float* params = (const float*)d_in[1];  // (2, NQ)
    const float* W      = (const float*)d_in[2];  // (OUT_DIM, FAN_IN)
    const float* b      = (const float*)d_in[3];  // (OUT_DIM,)
    float* out = (float*)d_out;

    float* A2 = (float*)d_ws;           // OUT_DIM floats
    float* B2 = A2 + OUT_DIM;           // OUT_DIM floats

    prep_kernel<<<1, OUT_DIM, 0, stream>>>(params, W, b, A2, B2);
    main_kernel<<<GRID, 256, 0, stream>>>(cond, A2, B2, out);
}